// Round 15
// baseline (214.383 us; speedup 1.0000x reference)
//
#include <hip/hip_runtime.h>
#include <math.h>

constexpr int B  = 2048;
constexpr int S  = 200;
constexpr int D  = 64;
constexpr int H  = 4;
constexpr int H1 = 64;
constexpr int H2 = 32;
constexpr int F  = 256;

constexpr int PK = 72;   // ushort pitch: 144 B rows (16B multiple), ~2-way banks

typedef short bf16x8 __attribute__((ext_vector_type(8)));
typedef float f32x4  __attribute__((ext_vector_type(4)));
typedef unsigned uint4v __attribute__((ext_vector_type(4)));

__device__ __forceinline__ unsigned cvtpk(float a, float b) {
    unsigned r;
    asm volatile("v_cvt_pk_bf16_f32 %0, %1, %2" : "=v"(r) : "v"(a), "v"(b));
    return r;
}
__device__ __forceinline__ float lo16f(unsigned w) { return __builtin_bit_cast(float, w << 16); }
__device__ __forceinline__ float hi16f(unsigned w) { return __builtin_bit_cast(float, w & 0xffff0000u); }

// ---- workspace layout (per-head constant images only, ~208 KB, L2-resident) ----
constexpr size_t SAD_OFF = 0;                        // 4h * 4096 f32
constexpr size_t SC_OFF  = SAD_OFF + 4 * 4096 * 4;
constexpr size_t SBD_OFF = SC_OFF  + 4 * 4096 * 4;
constexpr size_t W2I_OFF = SBD_OFF + 4 * 4096 * 4;   // 4h * 2048 ushort

// ---------------------------------------------------------------------------
// Build kernel: fragment-ordered per-head images of A+D, C, B-D (f32), W2 (bf16).
// Slot (f, l): f = kk*4+mt; k = 16*mt+(l&15); d0 = 32*kk+8*(l>>4); 8 d values.
// ---------------------------------------------------------------------------
__global__ __launch_bounds__(256) void build_kernel(
    const float* __restrict__ W1, const float* __restrict__ W2,
    float* __restrict__ sad, float* __restrict__ sc, float* __restrict__ sbd,
    ushort* __restrict__ w2i)
{
    const int h = blockIdx.x;
    const int t = threadIdx.x;
    const float* w1h = W1 + (size_t)h * F * H1;

    #pragma unroll
    for (int half = 0; half < 2; ++half) {
        const int sl = half * 256 + t;          // 0..511
        const int f  = sl >> 6, l = sl & 63;
        const int mt = f & 3, kk = f >> 2;
        const int k  = 16 * mt + (l & 15);
        const int d0 = 32 * kk + ((l >> 4) << 3);
        float vs[8], vc[8], vb[8];
        #pragma unroll
        for (int j = 0; j < 8; ++j) {
            const int d = d0 + j;
            float A  = w1h[d * 64 + k];
            float Bv = w1h[(64 + d) * 64 + k];
            float C  = w1h[(128 + d) * 64 + k];
            float Dv = w1h[(192 + d) * 64 + k];
            vs[j] = A + Dv; vc[j] = C; vb[j] = Bv - Dv;
        }
        const size_t off = ((size_t)h * 512 + sl) * 8;
        *(f32x4*)&sad[off]     = *(f32x4*)&vs[0];
        *(f32x4*)&sad[off + 4] = *(f32x4*)&vs[4];
        *(f32x4*)&sc [off]     = *(f32x4*)&vc[0];
        *(f32x4*)&sc [off + 4] = *(f32x4*)&vc[4];
        *(f32x4*)&sbd[off]     = *(f32x4*)&vb[0];
        *(f32x4*)&sbd[off + 4] = *(f32x4*)&vb[4];
    }

    {   // W2 fragment image: f2 = w*2+mt2; m = 16*mt2+(l&15); k20 = 32*w+8*(l>>4)
        const int f2 = t >> 6, l = t & 63;
        const int mt2 = f2 & 1, w = f2 >> 1;
        const int m = 16 * mt2 + (l & 15), k20 = 32 * w + ((l >> 4) << 3);
        const float* w2h = W2 + (size_t)h * H1 * H2;
        uint4v u = { cvtpk(w2h[(k20 + 0) * 32 + m], w2h[(k20 + 1) * 32 + m]),
                     cvtpk(w2h[(k20 + 2) * 32 + m], w2h[(k20 + 3) * 32 + m]),
                     cvtpk(w2h[(k20 + 4) * 32 + m], w2h[(k20 + 5) * 32 + m]),
                     cvtpk(w2h[(k20 + 6) * 32 + m], w2h[(k20 + 7) * 32 + m]) };
        *(uint4v*)&w2i[((size_t)h * 4 + f2) * 512 + l * 8] = u;
    }
}

// ---------------------------------------------------------------------------
// One block per batch row b; 8 waves; wave pair (sub 0/1) per head.
// Each wave runs 7 s-tiles (st = 6*sub + i; tile 6 computed by both subs —
// identical bits, benign). Scores exchanged via LDS; sub-0 wave does the
// head's softmax; attend splits s 100/100; projection over 8 wave-slices.
// ---------------------------------------------------------------------------
__global__ __launch_bounds__(512, 5) void fused_b_kernel(
    const float* __restrict__ query, const float* __restrict__ keys,
    const int* __restrict__ mask,
    const float* __restrict__ sad, const float* __restrict__ sc,
    const float* __restrict__ sbd, const ushort* __restrict__ w2i,
    const float* __restrict__ b1, const float* __restrict__ a1,
    const float* __restrict__ b2, const float* __restrict__ a2,
    const float* __restrict__ W3, const float* __restrict__ b3,
    const float* __restrict__ Wo, const float* __restrict__ bo,
    float* __restrict__ out)
{
    __shared__ ushort sK[200 * PK];        // keys bf16 [s][d]
    __shared__ ushort relay[8][16 * PK];   // per-wave relay; post-loop overlay:
                                           //   f32 [200..264) out partial, [264..328) proj partial
    __shared__ float  sSc[4][208];         // per-head scores -> weights

    const int b    = blockIdx.x;
    const int t    = threadIdx.x;
    const int lane = t & 63;
    const int wave = t >> 6;               // 0..7
    const int h    = wave >> 1;            // head
    const int sub  = wave & 1;             // half of the tile range
    const int g    = lane >> 4;
    const int ln16 = lane & 15;

    // ---- mask prefetch (softmax waves only) ----
    int mval[4] = {0, 0, 0, 0};
    if (sub == 0) {
        #pragma unroll
        for (int c = 0; c < 4; ++c) {
            int s = lane + 64 * c;
            mval[c] = (s < S) ? mask[(size_t)b * S + s] : 0;
        }
    }

    // ---- keys staging: 6 unrolled independent loads + tail, then writes ----
    {
        const float4* k4 = (const float4*)(keys + (size_t)b * S * D);
        float4 kv[6];
        #pragma unroll
        for (int i = 0; i < 6; ++i) kv[i] = k4[t + 512 * i];
        float4 kt;
        const bool tl = t < 128;
        if (tl) kt = k4[3072 + t];
        #pragma unroll
        for (int i = 0; i < 6; ++i) {
            const int idx = t + 512 * i;
            const int s = idx >> 4, dc = (idx & 15) * 4;
            *(uint2*)&sK[s * PK + dc] =
                make_uint2(cvtpk(kv[i].x, kv[i].y), cvtpk(kv[i].z, kv[i].w));
        }
        if (tl) {
            const int idx = 3072 + t;
            const int s = idx >> 4, dc = (idx & 15) * 4;
            *(uint2*)&sK[s * PK + dc] =
                make_uint2(cvtpk(kt.x, kt.y), cvtpk(kt.z, kt.w));
        }
    }

    // ---- register Weff build from fragment images + q (per wave) ----
    const float* qb = query + (size_t)b * D;
    bf16x8 wh[4][2];
    float qtp0 = 0.f, qtp1 = 0.f, qtp2 = 0.f, qtp3 = 0.f;
    #pragma unroll
    for (int kk = 0; kk < 2; ++kk) {
        const int d0 = 32 * kk + 8 * g;
        f32x4 q0 = *(const f32x4*)&qb[d0];
        f32x4 q1 = *(const f32x4*)&qb[d0 + 4];
        #pragma unroll
        for (int mt = 0; mt < 4; ++mt) {
            const int f = kk * 4 + mt;
            const size_t off = ((size_t)h * 512 + f * 64 + lane) * 8;
            f32x4 s0 = *(const f32x4*)&sad[off], s1 = *(const f32x4*)&sad[off + 4];
            f32x4 c0 = *(const f32x4*)&sc [off], c1 = *(const f32x4*)&sc [off + 4];
            f32x4 bd0 = *(const f32x4*)&sbd[off], bd1 = *(const f32x4*)&sbd[off + 4];
            float w0 = s0[0] + q0[0] * c0[0], w1 = s0[1] + q0[1] * c0[1];
            float w2 = s0[2] + q0[2] * c0[2], w3 = s0[3] + q0[3] * c0[3];
            float w4 = s1[0] + q1[0] * c1[0], w5 = s1[1] + q1[1] * c1[1];
            float w6 = s1[2] + q1[2] * c1[2], w7 = s1[3] + q1[3] * c1[3];
            uint4v u = { cvtpk(w0, w1), cvtpk(w2, w3), cvtpk(w4, w5), cvtpk(w6, w7) };
            wh[mt][kk] = __builtin_bit_cast(bf16x8, u);
            float d = q0[0]*bd0[0] + q0[1]*bd0[1] + q0[2]*bd0[2] + q0[3]*bd0[3]
                    + q1[0]*bd1[0] + q1[1]*bd1[1] + q1[2]*bd1[2] + q1[3]*bd1[3];
            if (mt == 0) qtp0 += d; else if (mt == 1) qtp1 += d;
            else if (mt == 2) qtp2 += d; else qtp3 += d;
        }
    }
    qtp0 += __shfl_xor(qtp0, 16); qtp0 += __shfl_xor(qtp0, 32);
    qtp1 += __shfl_xor(qtp1, 16); qtp1 += __shfl_xor(qtp1, 32);
    qtp2 += __shfl_xor(qtp2, 16); qtp2 += __shfl_xor(qtp2, 32);
    qtp3 += __shfl_xor(qtp3, 16); qtp3 += __shfl_xor(qtp3, 32);
    f32x4 qtv[4];
    #pragma unroll
    for (int mt = 0; mt < 4; ++mt) {
        float src = (mt == 0) ? qtp0 : (mt == 1) ? qtp1 : (mt == 2) ? qtp2 : qtp3;
        f32x4 b1v = *(const f32x4*)&b1[h * 64 + mt * 16 + 4 * g];
        f32x4 v;
        #pragma unroll
        for (int i = 0; i < 4; ++i) v[i] = __shfl(src, 4 * g + i) + b1v[i];
        qtv[mt] = v;
    }

    // ---- W2 fragments + constants ----
    bf16x8 w2f[2][2];
    #pragma unroll
    for (int w = 0; w < 2; ++w)
        #pragma unroll
        for (int mt2 = 0; mt2 < 2; ++mt2)
            w2f[w][mt2] = *(const bf16x8*)&w2i[((size_t)h * 4 + w * 2 + mt2) * 512 + lane * 8];
    f32x4 b2v[2], w3v[2];
    #pragma unroll
    for (int mt2 = 0; mt2 < 2; ++mt2) {
        b2v[mt2] = *(const f32x4*)&b2[h * 32 + mt2 * 16 + 4 * g];
        w3v[mt2] = *(const f32x4*)&W3[h * 32 + mt2 * 16 + 4 * g];
    }
    // prelu(x) = max(x, a*x) — exact for a <= 1 (this problem: a = 0.25)
    const float a1v = a1[h], a2v = a2[h], b3v = b3[h];

    __syncthreads();   // B1: sK ready

    ushort* myR = relay[wave];

    // ---- main loop: 7 s-tiles per wave (st = 6*sub + i), fully unrolled ----
    #pragma unroll
    for (int i = 0; i < 7; ++i) {
        const int st = 6 * sub + i;
        int srow = st * 16 + ln16;
        srow = srow > 199 ? 199 : srow;
        bf16x8 bk0 = *(const bf16x8*)&sK[srow * PK + 0  + 8 * g];
        bf16x8 bk1 = *(const bf16x8*)&sK[srow * PK + 32 + 8 * g];

        f32x4 acc[4] = { qtv[0], qtv[1], qtv[2], qtv[3] };
        #pragma unroll
        for (int mt = 0; mt < 4; ++mt)
            acc[mt] = __builtin_amdgcn_mfma_f32_16x16x32_bf16(wh[mt][0], bk0, acc[mt], 0, 0, 0);
        #pragma unroll
        for (int mt = 0; mt < 4; ++mt)
            acc[mt] = __builtin_amdgcn_mfma_f32_16x16x32_bf16(wh[mt][1], bk1, acc[mt], 0, 0, 0);

        #pragma unroll
        for (int mt = 0; mt < 4; ++mt) {
            float v0 = fmaxf(acc[mt][0], acc[mt][0] * a1v);
            float v1 = fmaxf(acc[mt][1], acc[mt][1] * a1v);
            float v2 = fmaxf(acc[mt][2], acc[mt][2] * a1v);
            float v3 = fmaxf(acc[mt][3], acc[mt][3] * a1v);
            *(uint2*)&myR[ln16 * PK + mt * 16 + 4 * g] =
                make_uint2(cvtpk(v0, v1), cvtpk(v2, v3));
        }

        f32x4 acc2[2] = { b2v[0], b2v[1] };
        #pragma unroll
        for (int w = 0; w < 2; ++w) {
            bf16x8 Bh = *(const bf16x8*)&myR[ln16 * PK + w * 32 + 8 * g];
            #pragma unroll
            for (int mt2 = 0; mt2 < 2; ++mt2)
                acc2[mt2] = __builtin_amdgcn_mfma_f32_16x16x32_bf16(w2f[w][mt2], Bh, acc2[mt2], 0, 0, 0);
        }

        float part = 0.f;
        #pragma unroll
        for (int mt2 = 0; mt2 < 2; ++mt2) {
            #pragma unroll
            for (int i2 = 0; i2 < 4; ++i2) {
                float v = fmaxf(acc2[mt2][i2], acc2[mt2][i2] * a2v);
                part += v * w3v[mt2][i2];
            }
        }
        part += __shfl_xor(part, 16);
        part += __shfl_xor(part, 32);
        const int s = st * 16 + ln16;
        if (lane < 16 && s < 200) sSc[h][s] = part + b3v;
    }
    __syncthreads();   // B2: all scores for the head in sSc[h]

    // ---- softmax: sub-0 wave of each head, in place ----
    if (sub == 0) {
        float v[4];
        float M = -INFINITY;
        #pragma unroll
        for (int c = 0; c < 4; ++c) {
            int s = lane + 64 * c;
            v[c] = (s < S && mval[c]) ? sSc[h][s] : -INFINITY;
            M = fmaxf(M, v[c]);
        }
        #pragma unroll
        for (int off = 32; off > 0; off >>= 1) M = fmaxf(M, __shfl_xor(M, off));
        float Z = 0.f, e[4];
        #pragma unroll
        for (int c = 0; c < 4; ++c) { e[c] = mval[c] ? __expf(v[c] - M) : 0.f; Z += e[c]; }
        #pragma unroll
        for (int off = 32; off > 0; off >>= 1) Z += __shfl_xor(Z, off);
        const float inv = Z > 0.f ? 1.f / Z : 0.f;
        #pragma unroll
        for (int c = 0; c < 4; ++c) { int s = lane + 64 * c; if (s < S) sSc[h][s] = e[c] * inv; }
    }
    __syncthreads();   // B3: weights ready

    // ---- attend: wave covers s in [100*sub, 100*sub+100), lane = (sg, d-quad) ----
    float* myF = (float*)myR;
    {
        const float* wsb = sSc[h];
        const int sg = lane >> 4, dq = ln16;
        float ax = 0.f, ay = 0.f, az = 0.f, aw = 0.f;
        #pragma unroll 5
        for (int i = 0; i < 25; ++i) {
            const int s = 100 * sub + sg * 25 + i;
            const float w = wsb[s];
            uint2 kv = *(const uint2*)&sK[s * PK + 4 * dq];
            ax += w * lo16f(kv.x); ay += w * hi16f(kv.x);
            az += w * lo16f(kv.y); aw += w * hi16f(kv.y);
        }
        ax += __shfl_xor(ax, 16); ay += __shfl_xor(ay, 16);
        az += __shfl_xor(az, 16); aw += __shfl_xor(aw, 16);
        ax += __shfl_xor(ax, 32); ay += __shfl_xor(ay, 32);
        az += __shfl_xor(az, 32); aw += __shfl_xor(aw, 32);
        if (lane < 16) {
            float4 o = { ax, ay, az, aw };
            *(float4*)&myF[200 + 4 * dq] = o;   // wave's out partial
        }
    }
    __syncthreads();   // B4: all out partials visible

    // ---- fused projection: wave covers d in [8*wave, 8*wave+8) ----
    {
        float p = 0.f;
        #pragma unroll
        for (int j = 0; j < 8; ++j) {
            const int d = 8 * wave + j;
            float cmb = 0.f;
            #pragma unroll
            for (int w2 = 0; w2 < 8; ++w2)
                cmb += ((const float*)relay[w2])[200 + d];
            p += 0.25f * cmb * Wo[d * 64 + lane];
        }
        myF[264 + lane] = p;
    }
    __syncthreads();   // B5: proj partials visible
    if (t < 64) {
        float o = bo[t];
        #pragma unroll
        for (int w2 = 0; w2 < 8; ++w2)
            o += ((const float*)relay[w2])[264 + t];
        out[(size_t)b * D + t] = o;
    }
}

// ---------------------------------------------------------------------------
extern "C" void kernel_launch(void* const* d_in, const int* in_sizes, int n_in,
                              void* d_out, int out_size, void* d_ws, size_t ws_size,
                              hipStream_t stream) {
    const float* query = (const float*)d_in[0];
    const float* keys  = (const float*)d_in[1];
    const int*   mask  = (const int*)d_in[2];
    const float* W1 = (const float*)d_in[3];
    const float* b1 = (const float*)d_in[4];
    const float* a1 = (const float*)d_in[5];
    const float* W2 = (const float*)d_in[6];
    const float* b2 = (const float*)d_in[7];
    const float* a2 = (const float*)d_in[8];
    const float* W3 = (const float*)d_in[9];
    const float* b3 = (const float*)d_in[10];
    const float* Wo = (const float*)d_in[11];
    const float* bo = (const float*)d_in[12];

    float* out  = (float*)d_out;
    char*  ws   = (char*)d_ws;
    float* sad  = (float*)(ws + SAD_OFF);
    float* sc   = (float*)(ws + SC_OFF);
    float* sbd  = (float*)(ws + SBD_OFF);
    ushort* w2i = (ushort*)(ws + W2I_OFF);

    build_kernel<<<dim3(H), 256, 0, stream>>>(W1, W2, sad, sc, sbd, w2i);
    fused_b_kernel<<<dim3(B), 512, 0, stream>>>(
        query, keys, mask, sad, sc, sbd, w2i, b1, a1, b2, a2, W3, b3,
        Wo, bo, out);
}

// Round 16
// 100.280 us; speedup vs baseline: 2.1378x; 2.1378x over previous
//
#include <hip/hip_runtime.h>
#include <math.h>

constexpr int B  = 2048;
constexpr int S  = 200;
constexpr int D  = 64;
constexpr int H  = 4;
constexpr int H1 = 64;
constexpr int H2 = 32;
constexpr int F  = 256;

constexpr int PK = 72;   // ushort pitch: 144 B rows (16B multiple), ~2-way banks

typedef short bf16x8 __attribute__((ext_vector_type(8)));
typedef float f32x4  __attribute__((ext_vector_type(4)));
typedef unsigned uint4v __attribute__((ext_vector_type(4)));

__device__ __forceinline__ unsigned cvtpk(float a, float b) {
    unsigned r;
    asm volatile("v_cvt_pk_bf16_f32 %0, %1, %2" : "=v"(r) : "v"(a), "v"(b));
    return r;
}
__device__ __forceinline__ float lo16f(unsigned w) { return __builtin_bit_cast(float, w << 16); }
__device__ __forceinline__ float hi16f(unsigned w) { return __builtin_bit_cast(float, w & 0xffff0000u); }

// ---- workspace layout (per-head constant images only, ~208 KB, L2-resident) ----
constexpr size_t SAD_OFF = 0;                        // 4h * 4096 f32
constexpr size_t SC_OFF  = SAD_OFF + 4 * 4096 * 4;
constexpr size_t SBD_OFF = SC_OFF  + 4 * 4096 * 4;
constexpr size_t W2I_OFF = SBD_OFF + 4 * 4096 * 4;   // 4h * 2048 ushort

// ---------------------------------------------------------------------------
// Build kernel: fragment-ordered per-head images of A+D, C, B-D (f32), W2 (bf16).
// Slot (f, l): f = kk*4+mt; k = 16*mt+(l&15); d0 = 32*kk+8*(l>>4); 8 d values.
// ---------------------------------------------------------------------------
__global__ __launch_bounds__(256) void build_kernel(
    const float* __restrict__ W1, const float* __restrict__ W2,
    float* __restrict__ sad, float* __restrict__ sc, float* __restrict__ sbd,
    ushort* __restrict__ w2i)
{
    const int h = blockIdx.x;
    const int t = threadIdx.x;
    const float* w1h = W1 + (size_t)h * F * H1;

    #pragma unroll
    for (int half = 0; half < 2; ++half) {
        const int sl = half * 256 + t;          // 0..511
        const int f  = sl >> 6, l = sl & 63;
        const int mt = f & 3, kk = f >> 2;
        const int k  = 16 * mt + (l & 15);
        const int d0 = 32 * kk + ((l >> 4) << 3);
        float vs[8], vc[8], vb[8];
        #pragma unroll
        for (int j = 0; j < 8; ++j) {
            const int d = d0 + j;
            float A  = w1h[d * 64 + k];
            float Bv = w1h[(64 + d) * 64 + k];
            float C  = w1h[(128 + d) * 64 + k];
            float Dv = w1h[(192 + d) * 64 + k];
            vs[j] = A + Dv; vc[j] = C; vb[j] = Bv - Dv;
        }
        const size_t off = ((size_t)h * 512 + sl) * 8;
        *(f32x4*)&sad[off]     = *(f32x4*)&vs[0];
        *(f32x4*)&sad[off + 4] = *(f32x4*)&vs[4];
        *(f32x4*)&sc [off]     = *(f32x4*)&vc[0];
        *(f32x4*)&sc [off + 4] = *(f32x4*)&vc[4];
        *(f32x4*)&sbd[off]     = *(f32x4*)&vb[0];
        *(f32x4*)&sbd[off + 4] = *(f32x4*)&vb[4];
    }

    {   // W2 fragment image: f2 = w*2+mt2; m = 16*mt2+(l&15); k20 = 32*w+8*(l>>4)
        const int f2 = t >> 6, l = t & 63;
        const int mt2 = f2 & 1, w = f2 >> 1;
        const int m = 16 * mt2 + (l & 15), k20 = 32 * w + ((l >> 4) << 3);
        const float* w2h = W2 + (size_t)h * H1 * H2;
        uint4v u = { cvtpk(w2h[(k20 + 0) * 32 + m], w2h[(k20 + 1) * 32 + m]),
                     cvtpk(w2h[(k20 + 2) * 32 + m], w2h[(k20 + 3) * 32 + m]),
                     cvtpk(w2h[(k20 + 4) * 32 + m], w2h[(k20 + 5) * 32 + m]),
                     cvtpk(w2h[(k20 + 6) * 32 + m], w2h[(k20 + 7) * 32 + m]) };
        *(uint4v*)&w2i[((size_t)h * 4 + f2) * 512 + l * 8] = u;
    }
}

// ---------------------------------------------------------------------------
// One block per batch row b; 8 waves; wave pair (sub 0/1) per head.
// Each wave runs 7 s-tiles (st = 6*sub + i; tile 6 computed by both subs —
// identical bits, benign). Scores exchanged via LDS; sub-0 wave does the
// head's softmax; attend splits s 100/100; projection over 8 wave-slices.
// __launch_bounds__(512, 2): cap 256 VGPR — round-15's (512,5) starved the
// allocator to 48 VGPR and spilled 254 MB. Hardware still schedules up to
// the LDS limit (3 blocks/CU).
// ---------------------------------------------------------------------------
__global__ __launch_bounds__(512, 2) void fused_b_kernel(
    const float* __restrict__ query, const float* __restrict__ keys,
    const int* __restrict__ mask,
    const float* __restrict__ sad, const float* __restrict__ sc,
    const float* __restrict__ sbd, const ushort* __restrict__ w2i,
    const float* __restrict__ b1, const float* __restrict__ a1,
    const float* __restrict__ b2, const float* __restrict__ a2,
    const float* __restrict__ W3, const float* __restrict__ b3,
    const float* __restrict__ Wo, const float* __restrict__ bo,
    float* __restrict__ out)
{
    __shared__ ushort sK[200 * PK];        // keys bf16 [s][d]
    __shared__ ushort relay[8][16 * PK];   // per-wave relay; post-loop overlay:
                                           //   f32 [200..264) out partial, [264..328) proj partial
    __shared__ float  sSc[4][208];         // per-head scores -> weights

    const int b    = blockIdx.x;
    const int t    = threadIdx.x;
    const int lane = t & 63;
    const int wave = t >> 6;               // 0..7
    const int h    = wave >> 1;            // head
    const int sub  = wave & 1;             // half of the tile range
    const int g    = lane >> 4;
    const int ln16 = lane & 15;

    // ---- mask prefetch (softmax waves only) ----
    int mval[4] = {0, 0, 0, 0};
    if (sub == 0) {
        #pragma unroll
        for (int c = 0; c < 4; ++c) {
            int s = lane + 64 * c;
            mval[c] = (s < S) ? mask[(size_t)b * S + s] : 0;
        }
    }

    // ---- keys staging: 6 unrolled independent loads + tail, then writes ----
    {
        const float4* k4 = (const float4*)(keys + (size_t)b * S * D);
        float4 kv[6];
        #pragma unroll
        for (int i = 0; i < 6; ++i) kv[i] = k4[t + 512 * i];
        float4 kt;
        const bool tl = t < 128;
        if (tl) kt = k4[3072 + t];
        #pragma unroll
        for (int i = 0; i < 6; ++i) {
            const int idx = t + 512 * i;
            const int s = idx >> 4, dc = (idx & 15) * 4;
            *(uint2*)&sK[s * PK + dc] =
                make_uint2(cvtpk(kv[i].x, kv[i].y), cvtpk(kv[i].z, kv[i].w));
        }
        if (tl) {
            const int idx = 3072 + t;
            const int s = idx >> 4, dc = (idx & 15) * 4;
            *(uint2*)&sK[s * PK + dc] =
                make_uint2(cvtpk(kt.x, kt.y), cvtpk(kt.z, kt.w));
        }
    }

    // ---- register Weff build from fragment images + q (per wave) ----
    const float* qb = query + (size_t)b * D;
    bf16x8 wh[4][2];
    float qtp0 = 0.f, qtp1 = 0.f, qtp2 = 0.f, qtp3 = 0.f;
    #pragma unroll
    for (int kk = 0; kk < 2; ++kk) {
        const int d0 = 32 * kk + 8 * g;
        f32x4 q0 = *(const f32x4*)&qb[d0];
        f32x4 q1 = *(const f32x4*)&qb[d0 + 4];
        #pragma unroll
        for (int mt = 0; mt < 4; ++mt) {
            const int f = kk * 4 + mt;
            const size_t off = ((size_t)h * 512 + f * 64 + lane) * 8;
            f32x4 s0 = *(const f32x4*)&sad[off], s1 = *(const f32x4*)&sad[off + 4];
            f32x4 c0 = *(const f32x4*)&sc [off], c1 = *(const f32x4*)&sc [off + 4];
            f32x4 bd0 = *(const f32x4*)&sbd[off], bd1 = *(const f32x4*)&sbd[off + 4];
            float w0 = s0[0] + q0[0] * c0[0], w1 = s0[1] + q0[1] * c0[1];
            float w2 = s0[2] + q0[2] * c0[2], w3 = s0[3] + q0[3] * c0[3];
            float w4 = s1[0] + q1[0] * c1[0], w5 = s1[1] + q1[1] * c1[1];
            float w6 = s1[2] + q1[2] * c1[2], w7 = s1[3] + q1[3] * c1[3];
            uint4v u = { cvtpk(w0, w1), cvtpk(w2, w3), cvtpk(w4, w5), cvtpk(w6, w7) };
            wh[mt][kk] = __builtin_bit_cast(bf16x8, u);
            float d = q0[0]*bd0[0] + q0[1]*bd0[1] + q0[2]*bd0[2] + q0[3]*bd0[3]
                    + q1[0]*bd1[0] + q1[1]*bd1[1] + q1[2]*bd1[2] + q1[3]*bd1[3];
            if (mt == 0) qtp0 += d; else if (mt == 1) qtp1 += d;
            else if (mt == 2) qtp2 += d; else qtp3 += d;
        }
    }
    qtp0 += __shfl_xor(qtp0, 16); qtp0 += __shfl_xor(qtp0, 32);
    qtp1 += __shfl_xor(qtp1, 16); qtp1 += __shfl_xor(qtp1, 32);
    qtp2 += __shfl_xor(qtp2, 16); qtp2 += __shfl_xor(qtp2, 32);
    qtp3 += __shfl_xor(qtp3, 16); qtp3 += __shfl_xor(qtp3, 32);
    f32x4 qtv[4];
    #pragma unroll
    for (int mt = 0; mt < 4; ++mt) {
        float src = (mt == 0) ? qtp0 : (mt == 1) ? qtp1 : (mt == 2) ? qtp2 : qtp3;
        f32x4 b1v = *(const f32x4*)&b1[h * 64 + mt * 16 + 4 * g];
        f32x4 v;
        #pragma unroll
        for (int i = 0; i < 4; ++i) v[i] = __shfl(src, 4 * g + i) + b1v[i];
        qtv[mt] = v;
    }

    // ---- W2 fragments + constants ----
    bf16x8 w2f[2][2];
    #pragma unroll
    for (int w = 0; w < 2; ++w)
        #pragma unroll
        for (int mt2 = 0; mt2 < 2; ++mt2)
            w2f[w][mt2] = *(const bf16x8*)&w2i[((size_t)h * 4 + w * 2 + mt2) * 512 + lane * 8];
    f32x4 b2v[2], w3v[2];
    #pragma unroll
    for (int mt2 = 0; mt2 < 2; ++mt2) {
        b2v[mt2] = *(const f32x4*)&b2[h * 32 + mt2 * 16 + 4 * g];
        w3v[mt2] = *(const f32x4*)&W3[h * 32 + mt2 * 16 + 4 * g];
    }
    // prelu(x) = max(x, a*x) — exact for a <= 1 (this problem: a = 0.25)
    const float a1v = a1[h], a2v = a2[h], b3v = b3[h];

    __syncthreads();   // B1: sK ready

    ushort* myR = relay[wave];

    // ---- main loop: 7 s-tiles per wave (st = 6*sub + i), fully unrolled ----
    #pragma unroll
    for (int i = 0; i < 7; ++i) {
        const int st = 6 * sub + i;
        int srow = st * 16 + ln16;
        srow = srow > 199 ? 199 : srow;
        bf16x8 bk0 = *(const bf16x8*)&sK[srow * PK + 0  + 8 * g];
        bf16x8 bk1 = *(const bf16x8*)&sK[srow * PK + 32 + 8 * g];

        f32x4 acc[4] = { qtv[0], qtv[1], qtv[2], qtv[3] };
        #pragma unroll
        for (int mt = 0; mt < 4; ++mt)
            acc[mt] = __builtin_amdgcn_mfma_f32_16x16x32_bf16(wh[mt][0], bk0, acc[mt], 0, 0, 0);
        #pragma unroll
        for (int mt = 0; mt < 4; ++mt)
            acc[mt] = __builtin_amdgcn_mfma_f32_16x16x32_bf16(wh[mt][1], bk1, acc[mt], 0, 0, 0);

        #pragma unroll
        for (int mt = 0; mt < 4; ++mt) {
            float v0 = fmaxf(acc[mt][0], acc[mt][0] * a1v);
            float v1 = fmaxf(acc[mt][1], acc[mt][1] * a1v);
            float v2 = fmaxf(acc[mt][2], acc[mt][2] * a1v);
            float v3 = fmaxf(acc[mt][3], acc[mt][3] * a1v);
            *(uint2*)&myR[ln16 * PK + mt * 16 + 4 * g] =
                make_uint2(cvtpk(v0, v1), cvtpk(v2, v3));
        }

        f32x4 acc2[2] = { b2v[0], b2v[1] };
        #pragma unroll
        for (int w = 0; w < 2; ++w) {
            bf16x8 Bh = *(const bf16x8*)&myR[ln16 * PK + w * 32 + 8 * g];
            #pragma unroll
            for (int mt2 = 0; mt2 < 2; ++mt2)
                acc2[mt2] = __builtin_amdgcn_mfma_f32_16x16x32_bf16(w2f[w][mt2], Bh, acc2[mt2], 0, 0, 0);
        }

        float part = 0.f;
        #pragma unroll
        for (int mt2 = 0; mt2 < 2; ++mt2) {
            #pragma unroll
            for (int i2 = 0; i2 < 4; ++i2) {
                float v = fmaxf(acc2[mt2][i2], acc2[mt2][i2] * a2v);
                part += v * w3v[mt2][i2];
            }
        }
        part += __shfl_xor(part, 16);
        part += __shfl_xor(part, 32);
        const int s = st * 16 + ln16;
        if (lane < 16 && s < 200) sSc[h][s] = part + b3v;
    }
    __syncthreads();   // B2: all scores for the head in sSc[h]

    // ---- softmax: sub-0 wave of each head, in place ----
    if (sub == 0) {
        float v[4];
        float M = -INFINITY;
        #pragma unroll
        for (int c = 0; c < 4; ++c) {
            int s = lane + 64 * c;
            v[c] = (s < S && mval[c]) ? sSc[h][s] : -INFINITY;
            M = fmaxf(M, v[c]);
        }
        #pragma unroll
        for (int off = 32; off > 0; off >>= 1) M = fmaxf(M, __shfl_xor(M, off));
        float Z = 0.f, e[4];
        #pragma unroll
        for (int c = 0; c < 4; ++c) { e[c] = mval[c] ? __expf(v[c] - M) : 0.f; Z += e[c]; }
        #pragma unroll
        for (int off = 32; off > 0; off >>= 1) Z += __shfl_xor(Z, off);
        const float inv = Z > 0.f ? 1.f / Z : 0.f;
        #pragma unroll
        for (int c = 0; c < 4; ++c) { int s = lane + 64 * c; if (s < S) sSc[h][s] = e[c] * inv; }
    }
    __syncthreads();   // B3: weights ready

    // ---- attend: wave covers s in [100*sub, 100*sub+100), lane = (sg, d-quad) ----
    float* myF = (float*)myR;
    {
        const float* wsb = sSc[h];
        const int sg = lane >> 4, dq = ln16;
        float ax = 0.f, ay = 0.f, az = 0.f, aw = 0.f;
        #pragma unroll 5
        for (int i = 0; i < 25; ++i) {
            const int s = 100 * sub + sg * 25 + i;
            const float w = wsb[s];
            uint2 kv = *(const uint2*)&sK[s * PK + 4 * dq];
            ax += w * lo16f(kv.x); ay += w * hi16f(kv.x);
            az += w * lo16f(kv.y); aw += w * hi16f(kv.y);
        }
        ax += __shfl_xor(ax, 16); ay += __shfl_xor(ay, 16);
        az += __shfl_xor(az, 16); aw += __shfl_xor(aw, 16);
        ax += __shfl_xor(ax, 32); ay += __shfl_xor(ay, 32);
        az += __shfl_xor(az, 32); aw += __shfl_xor(aw, 32);
        if (lane < 16) {
            float4 o = { ax, ay, az, aw };
            *(float4*)&myF[200 + 4 * dq] = o;   // wave's out partial
        }
    }
    __syncthreads();   // B4: all out partials visible

    // ---- fused projection: wave covers d in [8*wave, 8*wave+8) ----
    {
        float p = 0.f;
        #pragma unroll
        for (int j = 0; j < 8; ++j) {
            const int d = 8 * wave + j;
            float cmb = 0.f;
            #pragma unroll
            for (int w2 = 0; w2 < 8; ++w2)
                cmb += ((const float*)relay[w2])[200 + d];
            p += 0.25f * cmb * Wo[d * 64 + lane];
        }
        myF[264 + lane] = p;
    }
    __syncthreads();   // B5: proj partials visible
    if (t < 64) {
        float o = bo[t];
        #pragma unroll
        for (int w2 = 0; w2 < 8; ++w2)
            o += ((const float*)relay[w2])[264 + t];
        out[(size_t)b * D + t] = o;
    }
}

// ---------------------------------------------------------------------------
extern "C" void kernel_launch(void* const* d_in, const int* in_sizes, int n_in,
                              void* d_out, int out_size, void* d_ws, size_t ws_size,
                              hipStream_t stream) {
    const float* query = (const float*)d_in[0];
    const float* keys  = (const float*)d_in[1];
    const int*   mask  = (const int*)d_in[2];
    const float* W1 = (const float*)d_in[3];
    const float* b1 = (const float*)d_in[4];
    const float* a1 = (const float*)d_in[5];
    const float* W2 = (const float*)d_in[6];
    const float* b2 = (const float*)d_in[7];
    const float* a2 = (const float*)d_in[8];
    const float* W3 = (const float*)d_in[9];
    const float* b3 = (const float*)d_in[10];
    const float* Wo = (const float*)d_in[11];
    const float* bo = (const float*)d_in[12];

    float* out  = (float*)d_out;
    char*  ws   = (char*)d_ws;
    float* sad  = (float*)(ws + SAD_OFF);
    float* sc   = (float*)(ws + SC_OFF);
    float* sbd  = (float*)(ws + SBD_OFF);
    ushort* w2i = (ushort*)(ws + W2I_OFF);

    build_kernel<<<dim3(H), 256, 0, stream>>>(W1, W2, sad, sc, sbd, w2i);
    fused_b_kernel<<<dim3(B), 512, 0, stream>>>(
        query, keys, mask, sad, sc, sbd, w2i, b1, a1, b2, a2, W3, b3,
        Wo, bo, out);
}

// Round 17
// 62.079 us; speedup vs baseline: 3.4534x; 1.6154x over previous
//
#include <hip/hip_runtime.h>
#include <math.h>

constexpr int B  = 2048;
constexpr int S  = 200;
constexpr int D  = 64;
constexpr int H  = 4;
constexpr int H1 = 64;
constexpr int H2 = 32;
constexpr int F  = 256;

constexpr int PK = 72;   // ushort pitch: 144 B rows (16B multiple), ~2-way banks

typedef short bf16x8 __attribute__((ext_vector_type(8)));
typedef float f32x4  __attribute__((ext_vector_type(4)));
typedef unsigned uint4v __attribute__((ext_vector_type(4)));

__device__ __forceinline__ unsigned cvtpk(float a, float b) {
    unsigned r;
    asm volatile("v_cvt_pk_bf16_f32 %0, %1, %2" : "=v"(r) : "v"(a), "v"(b));
    return r;
}
__device__ __forceinline__ float lo16f(unsigned w) { return __builtin_bit_cast(float, w << 16); }
__device__ __forceinline__ float hi16f(unsigned w) { return __builtin_bit_cast(float, w & 0xffff0000u); }

// ---- workspace layout (per-head constant images only, ~208 KB, L2-resident) ----
constexpr size_t SAD_OFF = 0;                        // 4h * 4096 f32
constexpr size_t SC_OFF  = SAD_OFF + 4 * 4096 * 4;
constexpr size_t SBD_OFF = SC_OFF  + 4 * 4096 * 4;
constexpr size_t W2I_OFF = SBD_OFF + 4 * 4096 * 4;   // 4h * 2048 ushort

// ---------------------------------------------------------------------------
// Build kernel: fragment-ordered per-head images of A+D, C, B-D (f32), W2 (bf16).
// Slot (f, l): f = kk*4+mt; k = 16*mt+(l&15); d0 = 32*kk+8*(l>>4); 8 d values.
// 8 blocks (2 per head) to halve the serial pre-kernel latency.
// ---------------------------------------------------------------------------
__global__ __launch_bounds__(256) void build_kernel(
    const float* __restrict__ W1, const float* __restrict__ W2,
    float* __restrict__ sad, float* __restrict__ sc, float* __restrict__ sbd,
    ushort* __restrict__ w2i)
{
    const int h    = blockIdx.x >> 1;
    const int half = blockIdx.x & 1;
    const int t = threadIdx.x;
    const float* w1h = W1 + (size_t)h * F * H1;

    {
        const int sl = half * 256 + t;          // 0..511
        const int f  = sl >> 6, l = sl & 63;
        const int mt = f & 3, kk = f >> 2;
        const int k  = 16 * mt + (l & 15);
        const int d0 = 32 * kk + ((l >> 4) << 3);
        float vs[8], vc[8], vb[8];
        #pragma unroll
        for (int j = 0; j < 8; ++j) {
            const int d = d0 + j;
            float A  = w1h[d * 64 + k];
            float Bv = w1h[(64 + d) * 64 + k];
            float C  = w1h[(128 + d) * 64 + k];
            float Dv = w1h[(192 + d) * 64 + k];
            vs[j] = A + Dv; vc[j] = C; vb[j] = Bv - Dv;
        }
        const size_t off = ((size_t)h * 512 + sl) * 8;
        *(f32x4*)&sad[off]     = *(f32x4*)&vs[0];
        *(f32x4*)&sad[off + 4] = *(f32x4*)&vs[4];
        *(f32x4*)&sc [off]     = *(f32x4*)&vc[0];
        *(f32x4*)&sc [off + 4] = *(f32x4*)&vc[4];
        *(f32x4*)&sbd[off]     = *(f32x4*)&vb[0];
        *(f32x4*)&sbd[off + 4] = *(f32x4*)&vb[4];
    }

    if (half == 0) {   // W2 fragment image once per head
        const int f2 = t >> 6, l = t & 63;
        const int mt2 = f2 & 1, w = f2 >> 1;
        const int m = 16 * mt2 + (l & 15), k20 = 32 * w + ((l >> 4) << 3);
        const float* w2h = W2 + (size_t)h * H1 * H2;
        uint4v u = { cvtpk(w2h[(k20 + 0) * 32 + m], w2h[(k20 + 1) * 32 + m]),
                     cvtpk(w2h[(k20 + 2) * 32 + m], w2h[(k20 + 3) * 32 + m]),
                     cvtpk(w2h[(k20 + 4) * 32 + m], w2h[(k20 + 5) * 32 + m]),
                     cvtpk(w2h[(k20 + 6) * 32 + m], w2h[(k20 + 7) * 32 + m]) };
        *(uint4v*)&w2i[((size_t)h * 4 + f2) * 512 + l * 8] = u;
    }
}

// ---------------------------------------------------------------------------
// One block per batch row b; 4 waves; wave = head, end-to-end. 38 KB LDS;
// bound (256,3) — verified no spill at VGPR 84 (round 14).
// Scores in registers; two-pass softmax; projection fused.
// ---------------------------------------------------------------------------
__global__ __launch_bounds__(256, 3) void fused_b_kernel(
    const float* __restrict__ query, const float* __restrict__ keys,
    const int* __restrict__ mask,
    const float* __restrict__ sad, const float* __restrict__ sc,
    const float* __restrict__ sbd, const ushort* __restrict__ w2i,
    const float* __restrict__ b1, const float* __restrict__ a1,
    const float* __restrict__ b2, const float* __restrict__ a2,
    const float* __restrict__ W3, const float* __restrict__ b3,
    const float* __restrict__ Wo, const float* __restrict__ bo,
    float* __restrict__ out)
{
    __shared__ ushort sK[200 * PK];        // keys bf16 [s][d]
    __shared__ ushort relay[4][16 * PK];   // per-wave: relay; post-loop overlay:
                                           //   f32 [0..200) weights, [200..264) head-out, [264..328) proj partial

    const int b    = blockIdx.x;
    const int t    = threadIdx.x;
    const int lane = t & 63;
    const int h    = t >> 6;               // wave = head
    const int g    = lane >> 4;
    const int ln16 = lane & 15;

    // ---- mask: 4 coalesced loads -> 13-bit register mask in (st, ln16) layout ----
    unsigned mbits = 0;
    {
        int mval[4];
        #pragma unroll
        for (int c = 0; c < 4; ++c) {
            int s = lane + 64 * c;
            mval[c] = (s < S) ? mask[(size_t)b * S + s] : 0;
        }
        #pragma unroll
        for (int st = 0; st < 13; ++st) {
            const int src = 16 * (st & 3) + ln16;
            int v = (st >> 2) == 0 ? __shfl(mval[0], src)
                  : (st >> 2) == 1 ? __shfl(mval[1], src)
                  : (st >> 2) == 2 ? __shfl(mval[2], src)
                  :                  __shfl(mval[3], src);
            mbits |= (v != 0) ? (1u << st) : 0u;
        }
    }

    // ---- keys staging (bf16): two 6-load batches + tail, loads issued early ----
    {
        const float4* k4 = (const float4*)(keys + (size_t)b * S * D);
        float4 kv[6];
        #pragma unroll
        for (int i = 0; i < 6; ++i) kv[i] = k4[t + 256 * i];
        #pragma unroll
        for (int i = 0; i < 6; ++i) {
            const int idx = t + 256 * i;
            const int s = idx >> 4, dc = (idx & 15) * 4;
            *(uint2*)&sK[s * PK + dc] =
                make_uint2(cvtpk(kv[i].x, kv[i].y), cvtpk(kv[i].z, kv[i].w));
        }
        #pragma unroll
        for (int i = 0; i < 6; ++i) kv[i] = k4[t + 256 * (6 + i)];
        #pragma unroll
        for (int i = 0; i < 6; ++i) {
            const int idx = t + 256 * (6 + i);
            const int s = idx >> 4, dc = (idx & 15) * 4;
            *(uint2*)&sK[s * PK + dc] =
                make_uint2(cvtpk(kv[i].x, kv[i].y), cvtpk(kv[i].z, kv[i].w));
        }
        if (t < 128) {
            float4 kt = k4[3072 + t];
            const int idx = 3072 + t;
            const int s = idx >> 4, dc = (idx & 15) * 4;
            *(uint2*)&sK[s * PK + dc] =
                make_uint2(cvtpk(kt.x, kt.y), cvtpk(kt.z, kt.w));
        }
    }

    // ---- register Weff build from fragment images + q ----
    const float* qb = query + (size_t)b * D;
    bf16x8 wh[4][2];
    float qtp0 = 0.f, qtp1 = 0.f, qtp2 = 0.f, qtp3 = 0.f;
    #pragma unroll
    for (int kk = 0; kk < 2; ++kk) {
        const int d0 = 32 * kk + 8 * g;
        f32x4 q0 = *(const f32x4*)&qb[d0];
        f32x4 q1 = *(const f32x4*)&qb[d0 + 4];
        #pragma unroll
        for (int mt = 0; mt < 4; ++mt) {
            const int f = kk * 4 + mt;
            const size_t off = ((size_t)h * 512 + f * 64 + lane) * 8;
            f32x4 s0 = *(const f32x4*)&sad[off], s1 = *(const f32x4*)&sad[off + 4];
            f32x4 c0 = *(const f32x4*)&sc [off], c1 = *(const f32x4*)&sc [off + 4];
            f32x4 bd0 = *(const f32x4*)&sbd[off], bd1 = *(const f32x4*)&sbd[off + 4];
            float w0 = s0[0] + q0[0] * c0[0], w1 = s0[1] + q0[1] * c0[1];
            float w2 = s0[2] + q0[2] * c0[2], w3 = s0[3] + q0[3] * c0[3];
            float w4 = s1[0] + q1[0] * c1[0], w5 = s1[1] + q1[1] * c1[1];
            float w6 = s1[2] + q1[2] * c1[2], w7 = s1[3] + q1[3] * c1[3];
            uint4v u = { cvtpk(w0, w1), cvtpk(w2, w3), cvtpk(w4, w5), cvtpk(w6, w7) };
            wh[mt][kk] = __builtin_bit_cast(bf16x8, u);
            float d = q0[0]*bd0[0] + q0[1]*bd0[1] + q0[2]*bd0[2] + q0[3]*bd0[3]
                    + q1[0]*bd1[0] + q1[1]*bd1[1] + q1[2]*bd1[2] + q1[3]*bd1[3];
            if (mt == 0) qtp0 += d; else if (mt == 1) qtp1 += d;
            else if (mt == 2) qtp2 += d; else qtp3 += d;
        }
    }
    qtp0 += __shfl_xor(qtp0, 16); qtp0 += __shfl_xor(qtp0, 32);
    qtp1 += __shfl_xor(qtp1, 16); qtp1 += __shfl_xor(qtp1, 32);
    qtp2 += __shfl_xor(qtp2, 16); qtp2 += __shfl_xor(qtp2, 32);
    qtp3 += __shfl_xor(qtp3, 16); qtp3 += __shfl_xor(qtp3, 32);
    f32x4 qtv[4];
    #pragma unroll
    for (int mt = 0; mt < 4; ++mt) {
        float src = (mt == 0) ? qtp0 : (mt == 1) ? qtp1 : (mt == 2) ? qtp2 : qtp3;
        f32x4 b1v = *(const f32x4*)&b1[h * 64 + mt * 16 + 4 * g];
        f32x4 v;
        #pragma unroll
        for (int i = 0; i < 4; ++i) v[i] = __shfl(src, 4 * g + i) + b1v[i];
        qtv[mt] = v;
    }

    // ---- W2 fragments + constants ----
    bf16x8 w2f[2][2];
    #pragma unroll
    for (int w = 0; w < 2; ++w)
        #pragma unroll
        for (int mt2 = 0; mt2 < 2; ++mt2)
            w2f[w][mt2] = *(const bf16x8*)&w2i[((size_t)h * 4 + w * 2 + mt2) * 512 + lane * 8];
    f32x4 b2v[2], w3v[2];
    #pragma unroll
    for (int mt2 = 0; mt2 < 2; ++mt2) {
        b2v[mt2] = *(const f32x4*)&b2[h * 32 + mt2 * 16 + 4 * g];
        w3v[mt2] = *(const f32x4*)&W3[h * 32 + mt2 * 16 + 4 * g];
    }
    // prelu(x) = max(x, a*x) — exact for a <= 1 (this problem: a = 0.25)
    const float a1v = a1[h], a2v = a2[h], b3v = b3[h];

    __syncthreads();   // barrier 1: sK ready

    ushort* myR = relay[h];
    float sc13[13];

    // ---- main loop: 13 s-tiles, fully unrolled, scores stay in registers ----
    #pragma unroll
    for (int st = 0; st < 13; ++st) {
        int srow = st * 16 + ln16;
        srow = srow > 199 ? 199 : srow;
        bf16x8 bk0 = *(const bf16x8*)&sK[srow * PK + 0  + 8 * g];
        bf16x8 bk1 = *(const bf16x8*)&sK[srow * PK + 32 + 8 * g];

        f32x4 acc[4] = { qtv[0], qtv[1], qtv[2], qtv[3] };
        #pragma unroll
        for (int mt = 0; mt < 4; ++mt)
            acc[mt] = __builtin_amdgcn_mfma_f32_16x16x32_bf16(wh[mt][0], bk0, acc[mt], 0, 0, 0);
        #pragma unroll
        for (int mt = 0; mt < 4; ++mt)
            acc[mt] = __builtin_amdgcn_mfma_f32_16x16x32_bf16(wh[mt][1], bk1, acc[mt], 0, 0, 0);

        #pragma unroll
        for (int mt = 0; mt < 4; ++mt) {
            float v0 = fmaxf(acc[mt][0], acc[mt][0] * a1v);
            float v1 = fmaxf(acc[mt][1], acc[mt][1] * a1v);
            float v2 = fmaxf(acc[mt][2], acc[mt][2] * a1v);
            float v3 = fmaxf(acc[mt][3], acc[mt][3] * a1v);
            *(uint2*)&myR[ln16 * PK + mt * 16 + 4 * g] =
                make_uint2(cvtpk(v0, v1), cvtpk(v2, v3));
        }

        f32x4 acc2[2] = { b2v[0], b2v[1] };
        #pragma unroll
        for (int w = 0; w < 2; ++w) {
            bf16x8 Bh = *(const bf16x8*)&myR[ln16 * PK + w * 32 + 8 * g];
            #pragma unroll
            for (int mt2 = 0; mt2 < 2; ++mt2)
                acc2[mt2] = __builtin_amdgcn_mfma_f32_16x16x32_bf16(w2f[w][mt2], Bh, acc2[mt2], 0, 0, 0);
        }

        float part = 0.f;
        #pragma unroll
        for (int mt2 = 0; mt2 < 2; ++mt2) {
            #pragma unroll
            for (int i2 = 0; i2 < 4; ++i2) {
                float v = fmaxf(acc2[mt2][i2], acc2[mt2][i2] * a2v);
                part += v * w3v[mt2][i2];
            }
        }
        part += __shfl_xor(part, 16);
        part += __shfl_xor(part, 32);
        sc13[st] = part + b3v;   // every lane holds score[16*st + ln16]
    }

    // ---- two-pass softmax in registers (no e[] array; exp recomputed) ----
    float* ws = (float*)myR;    // relay region now dead for this wave
    {
        float M = -INFINITY;
        #pragma unroll
        for (int st = 0; st < 13; ++st)
            if ((mbits >> st) & 1) M = fmaxf(M, sc13[st]);
        #pragma unroll
        for (int off = 1; off < 16; off <<= 1) M = fmaxf(M, __shfl_xor(M, off));
        float Z = 0.f;
        #pragma unroll
        for (int st = 0; st < 13; ++st)
            Z += ((mbits >> st) & 1) ? __expf(sc13[st] - M) : 0.f;
        #pragma unroll
        for (int off = 1; off < 16; off <<= 1) Z += __shfl_xor(Z, off);
        const float inv = Z > 0.f ? 1.f / Z : 0.f;
        if (g == 0) {
            #pragma unroll
            for (int st = 0; st < 13; ++st) {
                const int s = st * 16 + ln16;
                if (st < 12 || ln16 < 8)
                    ws[s] = ((mbits >> st) & 1) ? __expf(sc13[st] - M) * inv : 0.f;
            }
        }
    }

    // ---- attend from LDS bf16 keys (weights broadcast from own slot) ----
    {
        const int sg = lane >> 4, dq = ln16;
        float ax = 0.f, ay = 0.f, az = 0.f, aw = 0.f;
        #pragma unroll 5
        for (int i = 0; i < 50; ++i) {
            const int s = sg * 50 + i;
            const float w = ws[s];
            uint2 kv = *(const uint2*)&sK[s * PK + 4 * dq];
            ax += w * lo16f(kv.x); ay += w * hi16f(kv.x);
            az += w * lo16f(kv.y); aw += w * hi16f(kv.y);
        }
        ax += __shfl_xor(ax, 16); ay += __shfl_xor(ay, 16);
        az += __shfl_xor(az, 16); aw += __shfl_xor(aw, 16);
        ax += __shfl_xor(ax, 32); ay += __shfl_xor(ay, 32);
        az += __shfl_xor(az, 32); aw += __shfl_xor(aw, 32);
        if (lane < 16) {
            float4 o = { ax, ay, az, aw };
            *(float4*)&ws[200 + 4 * dq] = o;   // head-out in own slot
        }
    }
    __syncthreads();   // barrier 2: all head-outs visible

    // ---- fused projection: wave h covers d in [16h, 16h+16) ----
    {
        float p = 0.f;
        #pragma unroll
        for (int j = 0; j < 16; ++j) {
            const int d = 16 * h + j;
            const float cmb = 0.25f * (((const float*)relay[0])[200 + d]
                                     + ((const float*)relay[1])[200 + d]
                                     + ((const float*)relay[2])[200 + d]
                                     + ((const float*)relay[3])[200 + d]);
            p += cmb * Wo[d * 64 + lane];
        }
        ws[264 + lane] = p;
    }
    __syncthreads();   // barrier 3: proj partials visible
    if (t < 64) {
        float o = bo[t] + ((const float*)relay[0])[264 + t]
                        + ((const float*)relay[1])[264 + t]
                        + ((const float*)relay[2])[264 + t]
                        + ((const float*)relay[3])[264 + t];
        out[(size_t)b * D + t] = o;
    }
}

// ---------------------------------------------------------------------------
extern "C" void kernel_launch(void* const* d_in, const int* in_sizes, int n_in,
                              void* d_out, int out_size, void* d_ws, size_t ws_size,
                              hipStream_t stream) {
    const float* query = (const float*)d_in[0];
    const float* keys  = (const float*)d_in[1];
    const int*   mask  = (const int*)d_in[2];
    const float* W1 = (const float*)d_in[3];
    const float* b1 = (const float*)d_in[4];
    const float* a1 = (const float*)d_in[5];
    const float* W2 = (const float*)d_in[6];
    const float* b2 = (const float*)d_in[7];
    const float* a2 = (const float*)d_in[8];
    const float* W3 = (const float*)d_in[9];
    const float* b3 = (const float*)d_in[10];
    const float* Wo = (const float*)d_in[11];
    const float* bo = (const float*)d_in[12];

    float* out  = (float*)d_out;
    char*  ws   = (char*)d_ws;
    float* sad  = (float*)(ws + SAD_OFF);
    float* sc   = (float*)(ws + SC_OFF);
    float* sbd  = (float*)(ws + SBD_OFF);
    ushort* w2i = (ushort*)(ws + W2I_OFF);

    build_kernel<<<dim3(H * 2), 256, 0, stream>>>(W1, W2, sad, sc, sbd, w2i);
    fused_b_kernel<<<dim3(B), 256, 0, stream>>>(
        query, keys, mask, sad, sc, sbd, w2i, b1, a1, b2, a2, W3, b3,
        Wo, bo, out);
}